// Round 31
// baseline (27.776 us; speedup 1.0000x reference)
//
#include <hip/hip_runtime.h>

// ChamferDistance: B=4, N=M=8192, fp32 3-D points.
// R31: fp16 K=7 x R20 GEOMETRY — isolates 2-blocks/CU on the champion's
// instruction stream. R30 regressed (27.3) but changed 3 things at once;
// this keeps R27's min3 pairing + write-once LDS combine and changes ONLY
// the block shape: 512 thr (8 waves), 128 rows/block, wave = rt(w&3) x
// col-half(w>>2), grid 512 = 2 blocks/CU @ 4 waves/SIMD -> barrier overlap
// (block B issues while block A waits). fp16 pack (~10 ops) makes the 2x
// pack redundancy ~0.3 µs (vs bf16's 3 µs, why R24 beat R20).
// Live ~72 regs < 128 cap at (512,4). LDS 16 KB -> 32 KB/CU.
// Math verified R27 (absmax 0.0156): fp16 K=7, zero-A-upper-half;
// A=[-2x(3), n1h, n1l, 1, 1, 0]; B=[y(3), 1, 1, n2h, n2l, 0], 16 B/pt.
// C layout 32x32 (dtype-independent): col=lane&31, row=(r&3)+8*(r>>2)+4*kg.
// Pre-commit: >= 25.4 -> resubmit R27 and declare convergence.

typedef _Float16 half8 __attribute__((ext_vector_type(8)));
typedef float    f32x16 __attribute__((ext_vector_type(16)));

#define B_       4
#define NPT      8192
#define THREADS  512
#define NROWBLK  64              // 128 rows per block
#define STAGEPTS 1024            // B points per LDS stage (16 KB packed)
#define NSTAGE   (NPT / STAGEPTS)    // 8
#define PINF_I   0x7f800000

__device__ __forceinline__ unsigned pkh(_Float16 a, _Float16 b) {
    union { _Float16 h; unsigned short u; } ua, ub;
    ua.h = a; ub.h = b;
    return (((unsigned)ub.u) << 16) | ua.u;
}

// Pack one row-point into the lane's A-fragment (kg=1 lanes: zeros -> kills
// the k8-15 half of the MFMA regardless of B's upper-half contents).
__device__ __forceinline__ half8 packA(const float* __restrict__ p, int kg) {
    half8 r = {};
    if (kg == 0) {
        float x0 = p[0], x1 = p[1], x2 = p[2];
        float n = x0*x0 + x1*x1 + x2*x2;
        _Float16 nh = (_Float16)n;
        _Float16 nl = (_Float16)(n - (float)nh);
        r[0] = (_Float16)(-2.f * x0);
        r[1] = (_Float16)(-2.f * x1);
        r[2] = (_Float16)(-2.f * x2);
        r[3] = nh; r[4] = nl;
        r[5] = (_Float16)1.f; r[6] = (_Float16)1.f;
        r[7] = (_Float16)0.f;
    }
    return r;
}

__global__ __launch_bounds__(THREADS, 4)   // 8 waves/block, 2 blocks/CU
void cd_fused(const float* __restrict__ xyz1, const float* __restrict__ xyz2,
              float* __restrict__ out) {
    __shared__ uint4 ysh[STAGEPTS];        // 16 KB stage; csh overlays (16 KB)

    int bid = blockIdx.x;
    const int rb   = bid & (NROWBLK - 1);  bid >>= 6;
    const int b    = bid & (B_ - 1);       bid >>= 2;
    const int pass = bid;                   // 0: dist1 (rows=cloud1), 1: dist2

    const float* __restrict__ xa = pass ? xyz2 : xyz1;   // row cloud
    const float* __restrict__ xb = pass ? xyz1 : xyz2;   // col cloud
    float* __restrict__ o = out + (size_t)pass * B_ * NPT;

    const int tid  = threadIdx.x;
    const int lane = tid & 63;
    const int w    = tid >> 6;             // 0..7
    const int rt   = w & 3;                // row-tile within block (4)
    const int h    = w >> 2;               // column half (0 or 1)
    const int l31  = lane & 31;
    const int kg   = lane >> 5;

    const size_t bbase = (size_t)b * NPT;
    const int    myRow = rb * 128 + rt * 32;

    // In-register A fragment (fp16, kg=1 -> zeros).
    half8 afrag = packA(xa + (bbase + myRow + l31) * 3, kg);

    f32x16 rmin;
    #pragma unroll
    for (int r = 0; r < 16; ++r) rmin[r] = __int_as_float(PINF_I);

    const half8* bsh = (const half8*)ysh;

    for (int s = 0; s < NSTAGE; ++s) {
        // Pack 1024 B points into LDS (TWO per thread), 16 B per point:
        // [y0, y1, y2, 1, 1, n2h, n2l, 0] as fp16.
        #pragma unroll
        for (int k = 0; k < 2; ++k) {
            const int p = k * THREADS + tid;
            const float* yp = xb + (bbase + (size_t)s * STAGEPTS + p) * 3;
            float y0 = yp[0], y1 = yp[1], y2 = yp[2];
            float n = y0*y0 + y1*y1 + y2*y2;
            _Float16 nh = (_Float16)n;
            _Float16 nl = (_Float16)(n - (float)nh);
            const _Float16 one = (_Float16)1.f;
            ysh[p] = make_uint4(
                pkh((_Float16)y0, (_Float16)y1),
                pkh((_Float16)y2, one),
                pkh(one, nh),
                pkh(nl, (_Float16)0.f));
        }
        __syncthreads();

        // This wave's column half: 16 tiles = 8 min3 pairs.
        #pragma unroll
        for (int pr = 0; pr < 8; ++pr) {
            const int t0 = h * 16 + pr * 2;
            half8 bf0 = bsh[t0 * 32 + l31];        // kg-pairs share addr
            half8 bf1 = bsh[(t0 + 1) * 32 + l31];  // (2-way broadcast, free)
            f32x16 z = {0.f};
            f32x16 accX = __builtin_amdgcn_mfma_f32_32x32x16_f16(afrag, bf0, z, 0, 0, 0);
            f32x16 accY = __builtin_amdgcn_mfma_f32_32x32x16_f16(afrag, bf1, z, 0, 0, 0);
            #pragma unroll
            for (int r = 0; r < 16; ++r)
                rmin[r] = fminf(fminf(accX[r], accY[r]), rmin[r]);   // v_min3_f32
        }
        __syncthreads();
    }

    // Cross-half combine via LDS (write-once, conflict-free [rt][r][lane]).
    float* csh = (float*)ysh;              // 4 * 16 * 64 floats = 16 KB
    if (h == 1) {
        #pragma unroll
        for (int r = 0; r < 16; ++r)
            csh[rt * 1024 + r * 64 + lane] = rmin[r];
    }
    __syncthreads();
    if (h == 0) {
        #pragma unroll
        for (int r = 0; r < 16; ++r) {
            float v = fminf(rmin[r], csh[rt * 1024 + r * 64 + lane]);
            v = fminf(v, __shfl_xor(v, 1, 64));
            v = fminf(v, __shfl_xor(v, 2, 64));
            v = fminf(v, __shfl_xor(v, 4, 64));
            v = fminf(v, __shfl_xor(v, 8, 64));
            v = fminf(v, __shfl_xor(v, 16, 64));
            if (l31 == 0) {
                int row = myRow + (r & 3) + 8 * (r >> 2) + 4 * kg;
                o[bbase + row] = fmaxf(v, 0.f);
            }
        }
    }
}

extern "C" void kernel_launch(void* const* d_in, const int* in_sizes, int n_in,
                              void* d_out, int out_size, void* d_ws, size_t ws_size,
                              hipStream_t stream) {
    const float* xyz1 = (const float*)d_in[0];
    const float* xyz2 = (const float*)d_in[1];
    // ONE launch, no workspace, no init, no atomics.
    cd_fused<<<2 * B_ * NROWBLK, THREADS, 0, stream>>>(xyz1, xyz2, (float*)d_out);
}

// Round 32
// 25.354 us; speedup vs baseline: 1.0955x; 1.0955x over previous
//
#include <hip/hip_runtime.h>

// ChamferDistance: B=4, N=M=8192, fp32 3-D points.
// R32 = R27 VERBATIM (champion, 25.4 µs) — convergence resubmission.
// Seven attempts to beat it all regressed (R25 28.1, R26 30.5, R28 fail,
// R29 28.1, R30 27.3, R31 27.8): barrier count, ds_read count, occupancy,
// blocks/CU, pack redundancy each attacked in isolation; every single-pipe
// reduction hurt. R27 is a schedule-local optimum balancing MFMA (6.9 µs) /
// LDS (10.2 µs) / VALU (~5 µs) across 16 waves.
// Structure: ONE kernel, no workspace/init/atomics. fp16 K=7 format
// (A=[-2x(3), n1h, n1l, 1, 1, 0], kg=1 lanes zero -> B upper half
// don't-care; B=[y(3), 1, 1, n2h, n2l, 0], 16 B/pt), in-register A-pack,
// in-kernel B-pack to 16 KB LDS stages (split layout, conflict-free),
// 1024 thr = 8 row-tiles x 2 col-halves, min3-paired MFMA loop, write-once
// LDS cross-half combine, direct store. absmax 0.0156 (<< 6.75e-2).
// C layout 32x32 (dtype-independent): col=lane&31, row=(r&3)+8*(r>>2)+4*kg.

typedef _Float16 half8 __attribute__((ext_vector_type(8)));
typedef float    f32x16 __attribute__((ext_vector_type(16)));

#define B_       4
#define NPT      8192
#define THREADS  1024
#define NROWBLK  32              // 256 rows per block
#define STAGEPTS 1024            // B points per LDS stage (16 KB packed)
#define NSTAGE   (NPT / STAGEPTS)    // 8
#define PINF_I   0x7f800000

__device__ __forceinline__ unsigned pkh(_Float16 a, _Float16 b) {
    union { _Float16 h; unsigned short u; } ua, ub;
    ua.h = a; ub.h = b;
    return (((unsigned)ub.u) << 16) | ua.u;
}

// Pack one row-point into the lane's A-fragment (kg=1 lanes: zeros -> kills
// the k8-15 half of the MFMA regardless of B's upper-half contents).
__device__ __forceinline__ half8 packA(const float* __restrict__ p, int kg) {
    half8 r = {};
    if (kg == 0) {
        float x0 = p[0], x1 = p[1], x2 = p[2];
        float n = x0*x0 + x1*x1 + x2*x2;
        _Float16 nh = (_Float16)n;
        _Float16 nl = (_Float16)(n - (float)nh);
        r[0] = (_Float16)(-2.f * x0);
        r[1] = (_Float16)(-2.f * x1);
        r[2] = (_Float16)(-2.f * x2);
        r[3] = nh; r[4] = nl;
        r[5] = (_Float16)1.f; r[6] = (_Float16)1.f;
        r[7] = (_Float16)0.f;
    }
    return r;
}

__global__ __launch_bounds__(THREADS, 4)   // 16 waves/block, 1 block/CU
void cd_fused(const float* __restrict__ xyz1, const float* __restrict__ xyz2,
              float* __restrict__ out) {
    __shared__ uint4 ysh[2048];            // 32 KB (stage uses 16 KB; csh 32 KB)

    int bid = blockIdx.x;
    const int rb   = bid & (NROWBLK - 1);  bid >>= 5;
    const int b    = bid & (B_ - 1);       bid >>= 2;
    const int pass = bid;                   // 0: dist1 (rows=cloud1), 1: dist2

    const float* __restrict__ xa = pass ? xyz2 : xyz1;   // row cloud
    const float* __restrict__ xb = pass ? xyz1 : xyz2;   // col cloud
    float* __restrict__ o = out + (size_t)pass * B_ * NPT;

    const int tid  = threadIdx.x;
    const int lane = tid & 63;
    const int w    = tid >> 6;             // 0..15
    const int rt   = w & 7;                // row-tile within block (8)
    const int h    = w >> 3;               // column half (0 or 1)
    const int l31  = lane & 31;
    const int kg   = lane >> 5;

    const size_t bbase = (size_t)b * NPT;
    const int    myRow = rb * 256 + rt * 32;

    // In-register A fragment (fp16, kg=1 -> zeros).
    half8 afrag = packA(xa + (bbase + myRow + l31) * 3, kg);

    f32x16 rmin;
    #pragma unroll
    for (int r = 0; r < 16; ++r) rmin[r] = __int_as_float(PINF_I);

    const half8* bsh = (const half8*)ysh;

    for (int s = 0; s < NSTAGE; ++s) {
        // Pack 1024 B points into LDS (ONE per thread), 16 B per point:
        // [y0, y1, y2, 1, 1, n2h, n2l, 0] as fp16.
        {
            const int p = tid;
            const float* yp = xb + (bbase + (size_t)s * STAGEPTS + p) * 3;
            float y0 = yp[0], y1 = yp[1], y2 = yp[2];
            float n = y0*y0 + y1*y1 + y2*y2;
            _Float16 nh = (_Float16)n;
            _Float16 nl = (_Float16)(n - (float)nh);
            const _Float16 one = (_Float16)1.f;
            ysh[p] = make_uint4(
                pkh((_Float16)y0, (_Float16)y1),
                pkh((_Float16)y2, one),
                pkh(one, nh),
                pkh(nl, (_Float16)0.f));
        }
        __syncthreads();

        // This wave's column half: 16 tiles = 8 min3 pairs.
        // All 64 lanes read point (t*32 + l31): kg-pairs share the address
        // (2-way broadcast, free); kg=1 operand content is don't-care.
        #pragma unroll
        for (int pr = 0; pr < 8; ++pr) {
            const int t0 = h * 16 + pr * 2;
            half8 bf0 = bsh[t0 * 32 + l31];
            half8 bf1 = bsh[(t0 + 1) * 32 + l31];
            f32x16 z = {0.f};
            f32x16 accX = __builtin_amdgcn_mfma_f32_32x32x16_f16(afrag, bf0, z, 0, 0, 0);
            f32x16 accY = __builtin_amdgcn_mfma_f32_32x32x16_f16(afrag, bf1, z, 0, 0, 0);
            #pragma unroll
            for (int r = 0; r < 16; ++r)
                rmin[r] = fminf(fminf(accX[r], accY[r]), rmin[r]);   // v_min3_f32
        }
        __syncthreads();
    }

    // Cross-half combine via LDS (reuse ysh; [rt][r][lane] = conflict-free).
    float* csh = (float*)ysh;              // 8 * 16 * 64 floats = 32 KB
    if (h == 1) {
        #pragma unroll
        for (int r = 0; r < 16; ++r)
            csh[rt * 1024 + r * 64 + lane] = rmin[r];
    }
    __syncthreads();
    if (h == 0) {
        #pragma unroll
        for (int r = 0; r < 16; ++r) {
            float v = fminf(rmin[r], csh[rt * 1024 + r * 64 + lane]);
            v = fminf(v, __shfl_xor(v, 1, 64));
            v = fminf(v, __shfl_xor(v, 2, 64));
            v = fminf(v, __shfl_xor(v, 4, 64));
            v = fminf(v, __shfl_xor(v, 8, 64));
            v = fminf(v, __shfl_xor(v, 16, 64));
            if (l31 == 0) {
                int row = myRow + (r & 3) + 8 * (r >> 2) + 4 * kg;
                o[bbase + row] = fmaxf(v, 0.f);
            }
        }
    }
}

extern "C" void kernel_launch(void* const* d_in, const int* in_sizes, int n_in,
                              void* d_out, int out_size, void* d_ws, size_t ws_size,
                              hipStream_t stream) {
    const float* xyz1 = (const float*)d_in[0];
    const float* xyz2 = (const float*)d_in[1];
    // ONE launch, no workspace, no init, no atomics.
    cd_fused<<<2 * B_ * NROWBLK, THREADS, 0, stream>>>(xyz1, xyz2, (float*)d_out);
}